// Round 8
// baseline (658.219 us; speedup 1.0000x reference)
//
#include <hip/hip_runtime.h>
#include <hip/hip_fp16.h>
#include <math.h>

#define N_NODES 30000
#define N_EDGES 480000
#define N_EDGES_SL (N_EDGES + N_NODES)
#define DIM_IN 256
#define F1 512   // HEADS*HID
#define HEADS 8
#define NGRAPH 512
#define NEG 0.2f
#define MB_TILES 235  // ceil(30000/128)

typedef __attribute__((ext_vector_type(8))) short short8;
typedef __attribute__((ext_vector_type(4))) float f32x4;

__device__ __forceinline__ float lrelu(float x) { return x < 0.f ? NEG * x : x; }
__device__ __forceinline__ float elu_(float x) { return x > 0.f ? x : expm1f(x); }

// split fp32 -> bf16 hi + bf16 lo (round-to-nearest-even both)
__device__ __forceinline__ void cvt_split(float a, unsigned short& h, unsigned short& l) {
    unsigned u = __float_as_uint(a);
    unsigned hb = (u + 0x7fffu + ((u >> 16) & 1u)) >> 16;
    h = (unsigned short)hb;
    float res = a - __uint_as_float(hb << 16);
    unsigned v = __float_as_uint(res);
    l = (unsigned short)((v + 0x7fffu + ((v >> 16) & 1u)) >> 16);
}

// async global->LDS, 16B per lane
__device__ __forceinline__ void glds16(const unsigned short* g, unsigned short* l) {
    __builtin_amdgcn_global_load_lds(
        (const __attribute__((address_space(1))) unsigned int*)g,
        (__attribute__((address_space(3))) unsigned int*)l, 16, 0, 0);
}

// ---------------- CSR build ----------------
__global__ void k_count(const int* __restrict__ ei, int* __restrict__ deg) {
    int i = blockIdx.x * blockDim.x + threadIdx.x;
    if (i < N_EDGES) atomicAdd(&deg[ei[N_EDGES + i]], 1);
}

__global__ __launch_bounds__(256) void k_scan(const int* __restrict__ deg,
                                              int* __restrict__ offs,
                                              int* __restrict__ cursor) {
    const int T = 256;
    const int CH = (N_NODES + T - 1) / T;
    int t = threadIdx.x;
    int lo = t * CH;
    int hi = min(lo + CH, N_NODES);
    int s = 0;
    for (int i = lo; i < hi; ++i) s += deg[i] + 1;  // +1: self-loop
    __shared__ int part[T];
    part[t] = s;
    __syncthreads();
    for (int off = 1; off < T; off <<= 1) {
        int v = (t >= off) ? part[t - off] : 0;
        __syncthreads();
        part[t] += v;
        __syncthreads();
    }
    int run = part[t] - s;
    for (int i = lo; i < hi; ++i) {
        int d = deg[i];           // read BEFORE cursor write (cursor aliases deg)
        offs[i] = run;
        cursor[i] = run;
        run += d + 1;
    }
    if (t == T - 1) offs[N_NODES] = part[T - 1];
}

// scatter edges; also record dst per CSR slot (needed by edge-weight kernels)
__global__ void k_scatter(const int* __restrict__ ei, int* __restrict__ cursor,
                          int* __restrict__ csrc, int* __restrict__ cdst) {
    int i = blockIdx.x * blockDim.x + threadIdx.x;
    if (i >= N_EDGES_SL) return;
    int s, d;
    if (i < N_EDGES) { s = ei[i]; d = ei[N_EDGES + i]; }
    else { s = d = i - N_EDGES; }
    int p = atomicAdd(&cursor[d], 1);
    csrc[p] = s;
    cdst[p] = d;
}

// graph segment boundaries from SORTED batch
__global__ void k_bounds(const int* __restrict__ batch, int* __restrict__ gstart) {
    int i = blockIdx.x * blockDim.x + threadIdx.x;
    if (i >= N_NODES) return;
    int b = batch[i];
    int pb = (i == 0) ? -1 : batch[i - 1];
    for (int g = pb + 1; g <= b; ++g) gstart[g] = i;
    if (i == N_NODES - 1)
        for (int g = b + 1; g <= NGRAPH; ++g) gstart[g] = N_NODES;
}

// ---------------- degree counting sort -> perm (similar-degree dsts adjacent) ------
__global__ __launch_bounds__(256) void k_hist(const int* __restrict__ offs,
                                              int* __restrict__ hist) {
    __shared__ int lh[256];
    lh[threadIdx.x] = 0;
    __syncthreads();
    int i = blockIdx.x * 256 + threadIdx.x;
    if (i < N_NODES) {
        int d = min(offs[i + 1] - offs[i], 255);
        atomicAdd(&lh[d], 1);
    }
    __syncthreads();
    if (lh[threadIdx.x]) atomicAdd(&hist[threadIdx.x], lh[threadIdx.x]);
}

__global__ __launch_bounds__(256) void k_hscan(const int* __restrict__ hist,
                                               int* __restrict__ cur) {
    __shared__ int p[256];
    int t = threadIdx.x;
    int v = hist[t];
    p[t] = v;
    __syncthreads();
    for (int off = 1; off < 256; off <<= 1) {
        int x = (t >= off) ? p[t - off] : 0;
        __syncthreads();
        p[t] += x;
        __syncthreads();
    }
    cur[t] = p[t] - v;  // exclusive base
}

__global__ __launch_bounds__(256) void k_psort(const int* __restrict__ offs,
                                               int* __restrict__ cur,
                                               int* __restrict__ perm) {
    int i = blockIdx.x * 256 + threadIdx.x;
    if (i >= N_NODES) return;
    int d = min(offs[i + 1] - offs[i], 255);
    perm[atomicAdd(&cur[d], 1)] = i;
}

// ---------------- pack A [M,K] fp32 -> [mb][kb][128][32] bf16 hi/lo ----------------
__global__ __launch_bounds__(256) void k_packA(const float* __restrict__ A,
                                               unsigned short* __restrict__ hi,
                                               unsigned short* __restrict__ lo,
                                               int M, int K) {
    int t = blockIdx.x * 256 + threadIdx.x;
    int KB = K >> 5;
    int MB = (M + 127) >> 7;
    int total = MB * KB * 512;
    if (t >= total) return;
    int k8 = t & 3;
    int ml = (t >> 2) & 127;
    int tmp = t >> 9;
    int kb = tmp % KB;
    int mb = tmp / KB;
    int m = mb * 128 + ml;
    int k0 = kb * 32 + k8 * 8;
    float v[8] = {0.f, 0.f, 0.f, 0.f, 0.f, 0.f, 0.f, 0.f};
    if (m < M) {
        float4 p0 = *(const float4*)(A + (size_t)m * K + k0);
        float4 p1 = *(const float4*)(A + (size_t)m * K + k0 + 4);
        v[0] = p0.x; v[1] = p0.y; v[2] = p0.z; v[3] = p0.w;
        v[4] = p1.x; v[5] = p1.y; v[6] = p1.z; v[7] = p1.w;
    }
    unsigned short h[8], l[8];
#pragma unroll
    for (int j = 0; j < 8; ++j) cvt_split(v[j], h[j], l[j]);
    size_t o = (size_t)t * 8;
    *(short8*)(hi + o) = *(short8*)h;
    *(short8*)(lo + o) = *(short8*)l;
}

// ---------------- pack W [K,Nn] fp32 -> [nb][kb][BN][32] bf16 hi/lo (n-major) -------
template <int BN>
__global__ __launch_bounds__(256) void k_packW(const float* __restrict__ W,
                                               unsigned short* __restrict__ hi,
                                               unsigned short* __restrict__ lo,
                                               int K, int Nn) {
    int t = blockIdx.x * 256 + threadIdx.x;
    int KB = K >> 5;
    int total = (Nn / BN) * KB * BN * 4;
    if (t >= total) return;
    constexpr int LB = (BN == 128) ? 7 : 6;
    int k8 = t & 3;
    int tmp = t >> 2;
    int nl = tmp & (BN - 1);
    int tmp2 = tmp >> LB;
    int kb = tmp2 % KB;
    int nb = tmp2 / KB;
    int n = nb * BN + nl;
    int k0 = kb * 32 + k8 * 8;
    unsigned short h[8], l[8];
#pragma unroll
    for (int j = 0; j < 8; ++j) cvt_split(W[(size_t)(k0 + j) * Nn + n], h[j], l[j]);
    size_t o = (size_t)t * 8;
    *(short8*)(hi + o) = *(short8*)h;
    *(short8*)(lo + o) = *(short8*)l;
}

// ---------------- split-bf16 MFMA GEMM, 8-head conv (Nn=512, BN=128, NF=4) ----------
// Epilogue: H fp16 head-split [head][node][64]; alphas [node][8] (vector-loadable
// by the edge-weight kernel).
template <int KB>
__global__ __launch_bounds__(256) void k_gemm8(const unsigned short* __restrict__ Ah,
                                               const unsigned short* __restrict__ Al,
                                               const unsigned short* __restrict__ Bh,
                                               const unsigned short* __restrict__ Bl,
                                               const float* __restrict__ a_src,
                                               const float* __restrict__ a_dst,
                                               __half* __restrict__ Hf,
                                               float* __restrict__ as_,
                                               float* __restrict__ ad_,
                                               int M) {
    __shared__ unsigned short sAh[4096], sAl[4096], sBh[4096], sBl[4096];
    const int tid = threadIdx.x, lane = tid & 63, wave = tid >> 6;
    const int mb = blockIdx.x, nb = blockIdx.y;
    const int wm = (wave >> 1) * 64;
    const int wn = (wave & 1) * 64;
    const int fr = lane & 15, quad = lane >> 4;

    const unsigned short* pAh = Ah + (size_t)mb * KB * 4096;
    const unsigned short* pAl = Al + (size_t)mb * KB * 4096;
    const unsigned short* pBh = Bh + (size_t)nb * KB * 4096;
    const unsigned short* pBl = Bl + (size_t)nb * KB * 4096;

    f32x4 acc[4][4];
#pragma unroll
    for (int i = 0; i < 4; ++i)
#pragma unroll
        for (int j = 0; j < 4; ++j) acc[i][j] = {0.f, 0.f, 0.f, 0.f};

    for (int kb = 0; kb < KB; ++kb) {
        const unsigned short* ah_g = pAh + kb * 4096;
        const unsigned short* al_g = pAl + kb * 4096;
        const unsigned short* bh_g = pBh + kb * 4096;
        const unsigned short* bl_g = pBl + kb * 4096;
#pragma unroll
        for (int s = 0; s < 2; ++s) {
            int sg = wave * 2 + s;
            glds16(ah_g + sg * 512 + lane * 8, &sAh[sg * 512]);
            glds16(al_g + sg * 512 + lane * 8, &sAl[sg * 512]);
            glds16(bh_g + sg * 512 + lane * 8, &sBh[sg * 512]);
            glds16(bl_g + sg * 512 + lane * 8, &sBl[sg * 512]);
        }
        __syncthreads();

        short8 af_h[4], af_l[4], bf_h[4], bf_l[4];
#pragma unroll
        for (int f = 0; f < 4; ++f) {
            int m = wm + f * 16 + fr;
            af_h[f] = *(const short8*)&sAh[m * 32 + quad * 8];
            af_l[f] = *(const short8*)&sAl[m * 32 + quad * 8];
            int n = wn + f * 16 + fr;
            bf_h[f] = *(const short8*)&sBh[n * 32 + quad * 8];
            bf_l[f] = *(const short8*)&sBl[n * 32 + quad * 8];
        }
#pragma unroll
        for (int i = 0; i < 4; ++i)
#pragma unroll
            for (int j = 0; j < 4; ++j) {
                acc[i][j] = __builtin_amdgcn_mfma_f32_16x16x32_bf16(af_h[i], bf_h[j], acc[i][j], 0, 0, 0);
                acc[i][j] = __builtin_amdgcn_mfma_f32_16x16x32_bf16(af_h[i], bf_l[j], acc[i][j], 0, 0, 0);
                acc[i][j] = __builtin_amdgcn_mfma_f32_16x16x32_bf16(af_l[i], bf_h[j], acc[i][j], 0, 0, 0);
            }
        __syncthreads();
    }
    // epilogue; C/D layout: col=lane&15, row=quad*4+reg
    const int head = (nb * 128 + wn) >> 6;  // wave's 64 cols = one head
    float avs[4], avd[4];
#pragma unroll
    for (int j = 0; j < 4; ++j) {
        avs[j] = a_src[head * 64 + j * 16 + fr];
        avd[j] = a_dst[head * 64 + j * 16 + fr];
    }
    __half* Hh = Hf + (size_t)head * N_NODES * 64;
#pragma unroll
    for (int i = 0; i < 4; ++i) {
#pragma unroll
        for (int r = 0; r < 4; ++r) {
            int row = mb * 128 + wm + i * 16 + quad * 4 + r;
            bool ok = row < M;
            float vs = 0.f, vd = 0.f;
#pragma unroll
            for (int j = 0; j < 4; ++j) {
                float c = acc[i][j][r];
                vs = fmaf(c, avs[j], vs);
                vd = fmaf(c, avd[j], vd);
                if (ok) Hh[(size_t)row * 64 + j * 16 + fr] = __float2half(c);
            }
#pragma unroll
            for (int off = 1; off < 16; off <<= 1) {
                vs += __shfl_xor(vs, off);
                vd += __shfl_xor(vd, off);
            }
            if (ok && fr == 0) {
                as_[(size_t)row * 8 + head] = vs;
                ad_[(size_t)row * 8 + head] = vd;
            }
        }
    }
}

// ---------------- split-bf16 MFMA GEMM, fp16 out (conv3: Nn=64) ----------
template <int KB, int NF>
__global__ __launch_bounds__(256) void k_gemm_mfma(const unsigned short* __restrict__ Ah,
                                                   const unsigned short* __restrict__ Al,
                                                   const unsigned short* __restrict__ Bh,
                                                   const unsigned short* __restrict__ Bl,
                                                   __half* __restrict__ C,
                                                   int M, int Nn) {
    constexpr int BN = NF * 32;
    constexpr int SBW = BN / 64;
    __shared__ unsigned short sAh[4096], sAl[4096], sBh[BN * 32], sBl[BN * 32];
    const int tid = threadIdx.x, lane = tid & 63, wave = tid >> 6;
    const int mb = blockIdx.x, nb = blockIdx.y;
    const int wm = (wave >> 1) * 64;
    const int wn = (wave & 1) * (BN / 2);
    const int fr = lane & 15, quad = lane >> 4;

    const unsigned short* pAh = Ah + (size_t)mb * KB * 4096;
    const unsigned short* pAl = Al + (size_t)mb * KB * 4096;
    const unsigned short* pBh = Bh + (size_t)nb * KB * (BN * 32);
    const unsigned short* pBl = Bl + (size_t)nb * KB * (BN * 32);

    f32x4 acc[4][NF];
#pragma unroll
    for (int i = 0; i < 4; ++i)
#pragma unroll
        for (int j = 0; j < NF; ++j) acc[i][j] = {0.f, 0.f, 0.f, 0.f};

    for (int kb = 0; kb < KB; ++kb) {
        const unsigned short* ah_g = pAh + kb * 4096;
        const unsigned short* al_g = pAl + kb * 4096;
        const unsigned short* bh_g = pBh + kb * (BN * 32);
        const unsigned short* bl_g = pBl + kb * (BN * 32);
#pragma unroll
        for (int s = 0; s < 2; ++s) {
            int sg = wave * 2 + s;
            glds16(ah_g + sg * 512 + lane * 8, &sAh[sg * 512]);
            glds16(al_g + sg * 512 + lane * 8, &sAl[sg * 512]);
        }
#pragma unroll
        for (int s = 0; s < SBW; ++s) {
            int sg = wave * SBW + s;
            glds16(bh_g + sg * 512 + lane * 8, &sBh[sg * 512]);
            glds16(bl_g + sg * 512 + lane * 8, &sBl[sg * 512]);
        }
        __syncthreads();

        short8 af_h[4], af_l[4], bf_h[NF], bf_l[NF];
#pragma unroll
        for (int f = 0; f < 4; ++f) {
            int m = wm + f * 16 + fr;
            af_h[f] = *(const short8*)&sAh[m * 32 + quad * 8];
            af_l[f] = *(const short8*)&sAl[m * 32 + quad * 8];
        }
#pragma unroll
        for (int f = 0; f < NF; ++f) {
            int n = wn + f * 16 + fr;
            bf_h[f] = *(const short8*)&sBh[n * 32 + quad * 8];
            bf_l[f] = *(const short8*)&sBl[n * 32 + quad * 8];
        }
#pragma unroll
        for (int i = 0; i < 4; ++i)
#pragma unroll
            for (int j = 0; j < NF; ++j) {
                acc[i][j] = __builtin_amdgcn_mfma_f32_16x16x32_bf16(af_h[i], bf_h[j], acc[i][j], 0, 0, 0);
                acc[i][j] = __builtin_amdgcn_mfma_f32_16x16x32_bf16(af_h[i], bf_l[j], acc[i][j], 0, 0, 0);
                acc[i][j] = __builtin_amdgcn_mfma_f32_16x16x32_bf16(af_l[i], bf_h[j], acc[i][j], 0, 0, 0);
            }
        __syncthreads();
    }
#pragma unroll
    for (int i = 0; i < 4; ++i) {
#pragma unroll
        for (int r = 0; r < 4; ++r) {
            int row = mb * 128 + wm + i * 16 + quad * 4 + r;
            if (row < M) {
#pragma unroll
                for (int j = 0; j < NF; ++j)
                    C[(size_t)row * Nn + nb * BN + wn + j * 16 + fr] =
                        __float2half(acc[i][j][r]);
            }
        }
    }
}

// ---------------- per-edge softmax weights, all 8 heads (one pass over CSR) --------
__global__ __launch_bounds__(256) void k_ew8(const float* __restrict__ as_,
                                             const float* __restrict__ ad_,
                                             const int* __restrict__ csrc,
                                             const int* __restrict__ cdst,
                                             float* __restrict__ wbuf) {
    int e = blockIdx.x * 256 + threadIdx.x;
    if (e >= N_EDGES_SL) return;
    int s = csrc[e], d = cdst[e];
    float4 a0 = *(const float4*)(as_ + (size_t)s * 8);
    float4 a1 = *(const float4*)(as_ + (size_t)s * 8 + 4);
    float4 d0 = *(const float4*)(ad_ + (size_t)d * 8);
    float4 d1 = *(const float4*)(ad_ + (size_t)d * 8 + 4);
    float4 w0, w1;
    w0.x = __expf(lrelu(a0.x + d0.x));
    w0.y = __expf(lrelu(a0.y + d0.y));
    w0.z = __expf(lrelu(a0.z + d0.z));
    w0.w = __expf(lrelu(a0.w + d0.w));
    w1.x = __expf(lrelu(a1.x + d1.x));
    w1.y = __expf(lrelu(a1.y + d1.y));
    w1.z = __expf(lrelu(a1.z + d1.z));
    w1.w = __expf(lrelu(a1.w + d1.w));
    *(float4*)(wbuf + (size_t)e * 8) = w0;
    *(float4*)(wbuf + (size_t)e * 8 + 4) = w1;
}

// per-edge weights, 1 head (conv3)
__global__ __launch_bounds__(256) void k_ew1(const float* __restrict__ as_,
                                             const float* __restrict__ ad_,
                                             const int* __restrict__ csrc,
                                             const int* __restrict__ cdst,
                                             float* __restrict__ w3) {
    int e = blockIdx.x * 256 + threadIdx.x;
    if (e >= N_EDGES_SL) return;
    w3[e] = __expf(lrelu(as_[csrc[e]] + ad_[cdst[e]]));
}

// w * h (8 fp16 channels) -> fp32 acc; written to coax v_fma_mix_f32 (cvt folded)
__device__ __forceinline__ void edge_fma(float w, uint4 u, float* a) {
    const _Float16* hp = (const _Float16*)&u;
#pragma unroll
    for (int k = 0; k < 8; ++k) a[k] = fmaf(w, (float)hp[k], a[k]);
}

// ---------------- softmax-aggregate (8 heads), head-split, XCD-affine --------------
// One wave = 8 dsts x 1 head (dsts via degree-sorted perm -> equal loop trips).
// Per edge: csrc idx + precomputed w + 16B H gather + 8 mix-fma + s+=w. No exp,
// no reductions, no LDS. head = blockIdx&7 pins head to XCD (2048 blocks).
__global__ __launch_bounds__(256) void k_agg8(const __half* __restrict__ Hf,
                                              const float* __restrict__ wbuf,
                                              const int* __restrict__ offs,
                                              const int* __restrict__ csrc,
                                              const int* __restrict__ perm,
                                              const float* __restrict__ bias,
                                              unsigned short* __restrict__ outh,
                                              unsigned short* __restrict__ outl) {
    const int head = blockIdx.x & 7;
    const int bg = blockIdx.x >> 3;  // 0..255
    const int wave = threadIdx.x >> 6, lane = threadIdx.x & 63;
    const int g = lane >> 3, cl = lane & 7;
    const __half* Hh = Hf + (size_t)head * N_NODES * 64;
    float bia[8];
#pragma unroll
    for (int j = 0; j < 8; ++j) bia[j] = bias[head * 64 + cl * 8 + j];

    for (int i0 = (bg * 4 + wave) * 8; i0 < N_NODES; i0 += 8192) {
        int dst = perm[i0 + g];
        int beg = offs[dst], end = offs[dst + 1];
        const int* cp = csrc + beg;
        const float* wp = wbuf + (size_t)beg * 8 + head;
        int deg = end - beg;
        float s = 0.f;
        float a[8] = {0.f, 0.f, 0.f, 0.f, 0.f, 0.f, 0.f, 0.f};
        float b[8] = {0.f, 0.f, 0.f, 0.f, 0.f, 0.f, 0.f, 0.f};
        int loc = 0;
        for (; loc + 3 < deg; loc += 4) {
            int s0 = cp[loc], s1 = cp[loc + 1], s2 = cp[loc + 2], s3 = cp[loc + 3];
            float w0 = wp[(size_t)loc * 8];
            float w1 = wp[(size_t)(loc + 1) * 8];
            float w2 = wp[(size_t)(loc + 2) * 8];
            float w3 = wp[(size_t)(loc + 3) * 8];
            uint4 u0 = *(const uint4*)(Hh + (size_t)s0 * 64 + cl * 8);
            uint4 u1 = *(const uint4*)(Hh + (size_t)s1 * 64 + cl * 8);
            uint4 u2 = *(const uint4*)(Hh + (size_t)s2 * 64 + cl * 8);
            uint4 u3 = *(const uint4*)(Hh + (size_t)s3 * 64 + cl * 8);
            s += (w0 + w1) + (w2 + w3);
            edge_fma(w0, u0, a);
            edge_fma(w1, u1, b);
            edge_fma(w2, u2, a);
            edge_fma(w3, u3, b);
        }
        for (; loc < deg; ++loc) {
            int s0 = cp[loc];
            float w = wp[(size_t)loc * 8];
            uint4 u = *(const uint4*)(Hh + (size_t)s0 * 64 + cl * 8);
            s += w;
            edge_fma(w, u, a);
        }
        float inv = 1.f / s;
        float o[8];
#pragma unroll
        for (int k = 0; k < 8; ++k) o[k] = elu_((a[k] + b[k]) * inv + bia[k]);
        unsigned short h[8], l[8];
#pragma unroll
        for (int k = 0; k < 8; ++k) cvt_split(o[k], h[k], l[k]);
        // packed A-tile write: global ch c0 = head*64 + cl*8
        int c0 = head * 64 + cl * 8;
        int kb = c0 >> 5, kl = c0 & 31;
        int mb = dst >> 7, ml = dst & 127;
        size_t oo = (((size_t)(mb * 16 + kb) * 128 + ml) * 32 + kl);
        *(short8*)(outh + oo) = *(short8*)h;
        *(short8*)(outl + oo) = *(short8*)l;
    }
}

// ---------------- conv3: 1 head x 64 ch ----------------
__global__ __launch_bounds__(256) void k_alphas1(const __half* __restrict__ H,
                                                 const float* __restrict__ a_src,
                                                 const float* __restrict__ a_dst,
                                                 float* __restrict__ as_,
                                                 float* __restrict__ ad_) {
    int wid = blockIdx.x * 4 + (threadIdx.x >> 6);
    int lane = threadIdx.x & 63;
    if (wid >= N_NODES) return;
    float h = __half2float(H[(size_t)wid * 64 + lane]);
    float ps = h * a_src[lane];
    float pd = h * a_dst[lane];
#pragma unroll
    for (int off = 1; off < 64; off <<= 1) {
        ps += __shfl_xor(ps, off);
        pd += __shfl_xor(pd, off);
    }
    if (lane == 0) { as_[wid] = ps; ad_[wid] = pd; }
}

// single-pass; precomputed w; writes h3 [node][64] fp32
__global__ __launch_bounds__(256) void k_agg1(const __half* __restrict__ Hf,
                                              const float* __restrict__ w3,
                                              const int* __restrict__ offs,
                                              const int* __restrict__ csrc,
                                              const int* __restrict__ perm,
                                              const float* __restrict__ bias,
                                              float* __restrict__ h3) {
    const int wave = threadIdx.x >> 6, lane = threadIdx.x & 63;
    const int g = lane >> 3, cl = lane & 7;
    int i0 = (blockIdx.x * 4 + wave) * 8;  // grid 940 -> 3760 octets >= 3750
    if (i0 >= N_NODES) return;
    int dst = perm[i0 + g];
    float bia[8];
#pragma unroll
    for (int j = 0; j < 8; ++j) bia[j] = bias[cl * 8 + j];
    int beg = offs[dst], end = offs[dst + 1];
    const int* cp = csrc + beg;
    const float* wp = w3 + beg;
    int deg = end - beg;
    float s = 0.f;
    float a[8] = {0.f, 0.f, 0.f, 0.f, 0.f, 0.f, 0.f, 0.f};
    float b[8] = {0.f, 0.f, 0.f, 0.f, 0.f, 0.f, 0.f, 0.f};
    int loc = 0;
    for (; loc + 3 < deg; loc += 4) {
        int s0 = cp[loc], s1 = cp[loc + 1], s2 = cp[loc + 2], s3 = cp[loc + 3];
        float w0 = wp[loc], w1 = wp[loc + 1], w2 = wp[loc + 2], w3v = wp[loc + 3];
        uint4 u0 = *(const uint4*)(Hf + (size_t)s0 * 64 + cl * 8);
        uint4 u1 = *(const uint4*)(Hf + (size_t)s1 * 64 + cl * 8);
        uint4 u2 = *(const uint4*)(Hf + (size_t)s2 * 64 + cl * 8);
        uint4 u3 = *(const uint4*)(Hf + (size_t)s3 * 64 + cl * 8);
        s += (w0 + w1) + (w2 + w3v);
        edge_fma(w0, u0, a);
        edge_fma(w1, u1, b);
        edge_fma(w2, u2, a);
        edge_fma(w3v, u3, b);
    }
    for (; loc < deg; ++loc) {
        int s0 = cp[loc];
        float w = wp[loc];
        uint4 u = *(const uint4*)(Hf + (size_t)s0 * 64 + cl * 8);
        s += w;
        edge_fma(w, u, a);
    }
    float inv = 1.f / s;
    float o[8];
#pragma unroll
    for (int k = 0; k < 8; ++k) o[k] = elu_((a[k] + b[k]) * inv + bia[k]);
    float* op = h3 + (size_t)dst * 64 + cl * 8;
    *(float4*)op = make_float4(o[0], o[1], o[2], o[3]);
    *(float4*)(op + 4) = make_float4(o[4], o[5], o[6], o[7]);
}

// ---------------- segmented mean-pool (sorted batch) + fc, no atomics ----------
__global__ __launch_bounds__(128) void k_poolfc(const float* __restrict__ h3,
                                                const int* __restrict__ gstart,
                                                const float* __restrict__ W,
                                                const float* __restrict__ b,
                                                float* __restrict__ out) {
    int g = blockIdx.x;
    int t = threadIdx.x;  // 128
    int s0 = gstart[g], s1 = gstart[g + 1];
    int c = t & 63, half = t >> 6;
    float acc = 0.f;
    for (int r = s0 + half; r < s1; r += 2) acc += h3[(size_t)r * 64 + c];
    __shared__ float p2[128];
    __shared__ float p[64];
    p2[t] = acc;
    __syncthreads();
    if (t < 64) {
        float cntf = (float)(s1 - s0);
        p[t] = (p2[t] + p2[t + 64]) / fmaxf(cntf, 1.f);
    }
    __syncthreads();
    float o = b[t];
#pragma unroll
    for (int k = 0; k < 64; ++k) o = fmaf(p[k], W[k * 128 + t], o);
    out[g * 128 + t] = o;
}

extern "C" void kernel_launch(void* const* d_in, const int* in_sizes, int n_in,
                              void* d_out, int out_size, void* d_ws, size_t ws_size,
                              hipStream_t stream) {
    const float* x     = (const float*)d_in[0];
    const int*   ei    = (const int*)d_in[1];
    const int*   batch = (const int*)d_in[2];
    const float* W1    = (const float*)d_in[3];
    const float* as1   = (const float*)d_in[4];
    const float* ad1   = (const float*)d_in[5];
    const float* b1    = (const float*)d_in[6];
    const float* W2    = (const float*)d_in[7];
    const float* as2   = (const float*)d_in[8];
    const float* ad2   = (const float*)d_in[9];
    const float* b2    = (const float*)d_in[10];
    const float* W3    = (const float*)d_in[11];
    const float* as3   = (const float*)d_in[12];
    const float* ad3   = (const float*)d_in[13];
    const float* b3    = (const float*)d_in[14];
    const float* Wfc   = (const float*)d_in[15];
    const float* bfc   = (const float*)d_in[16];
    float* out = (float*)d_out;

    char* ws = (char*)d_ws;
    size_t off = 0;
    auto alloc = [&](size_t bytes) -> void* {
        void* p = ws + off;
        off += (bytes + 255) & ~(size_t)255;
        return p;
    };
    __half* Hf = (__half*)alloc((size_t)HEADS * N_NODES * 64 * 2);  // [head][node][64]
    __half* Hf3 = (__half*)alloc((size_t)N_NODES * 64 * 2);
    float* h3 = (float*)alloc((size_t)N_NODES * 64 * 4);
    unsigned short* Ah = (unsigned short*)alloc((size_t)MB_TILES * 16 * 4096 * 2);
    unsigned short* Al = (unsigned short*)alloc((size_t)MB_TILES * 16 * 4096 * 2);
    unsigned short* Wh = (unsigned short*)alloc((size_t)262144 * 2);
    unsigned short* Wl = (unsigned short*)alloc((size_t)262144 * 2);
    float* asb   = (float*)alloc((size_t)N_NODES * 8 * 4);   // [node][8]
    float* adb   = (float*)alloc((size_t)N_NODES * 8 * 4);
    float* asb1  = (float*)alloc((size_t)N_NODES * 4);       // conv3 [node]
    float* adb1  = (float*)alloc((size_t)N_NODES * 4);
    float* wbuf  = (float*)alloc((size_t)N_EDGES_SL * 8 * 4);  // per-edge w, 8 heads
    float* w3    = (float*)alloc((size_t)N_EDGES_SL * 4);
    int*   offs  = (int*)alloc((N_NODES + 1) * 4);
    int*   deg   = (int*)alloc(N_NODES * 4);   // reused as scatter cursor
    int*   csrc  = (int*)alloc((size_t)N_EDGES_SL * 4);
    int*   cdst  = (int*)alloc((size_t)N_EDGES_SL * 4);
    int*   perm  = (int*)alloc(N_NODES * 4);
    int*   hist  = (int*)alloc(256 * 4);
    int*   cur   = (int*)alloc(256 * 4);
    int*   gstart= (int*)alloc((NGRAPH + 1) * 4);

    hipMemsetAsync(deg, 0, N_NODES * 4, stream);
    hipMemsetAsync(hist, 0, 256 * 4, stream);

    k_count<<<(N_EDGES + 255) / 256, 256, 0, stream>>>(ei, deg);
    k_scan<<<1, 256, 0, stream>>>(deg, offs, deg);
    k_scatter<<<(N_EDGES_SL + 255) / 256, 256, 0, stream>>>(ei, deg, csrc, cdst);
    k_bounds<<<(N_NODES + 255) / 256, 256, 0, stream>>>(batch, gstart);
    // degree-sorted permutation
    k_hist<<<(N_NODES + 255) / 256, 256, 0, stream>>>(offs, hist);
    k_hscan<<<1, 256, 0, stream>>>(hist, cur);
    k_psort<<<(N_NODES + 255) / 256, 256, 0, stream>>>(offs, cur, perm);

    // ---- conv1: K=256 (KB=8) ----
    k_packA<<<(MB_TILES * 8 * 512 + 255) / 256, 256, 0, stream>>>(x, Ah, Al, N_NODES, DIM_IN);
    k_packW<128><<<(4 * 8 * 128 * 4 + 255) / 256, 256, 0, stream>>>(W1, Wh, Wl, DIM_IN, F1);
    k_gemm8<8><<<dim3(MB_TILES, 4), 256, 0, stream>>>(Ah, Al, Wh, Wl, as1, ad1, Hf, asb, adb, N_NODES);
    k_ew8<<<(N_EDGES_SL + 255) / 256, 256, 0, stream>>>(asb, adb, csrc, cdst, wbuf);
    k_agg8<<<2048, 256, 0, stream>>>(Hf, wbuf, offs, csrc, perm, b1, Ah, Al);

    // ---- conv2: K=512 (KB=16) ----
    k_packW<128><<<(4 * 16 * 128 * 4 + 255) / 256, 256, 0, stream>>>(W2, Wh, Wl, F1, F1);
    k_gemm8<16><<<dim3(MB_TILES, 4), 256, 0, stream>>>(Ah, Al, Wh, Wl, as2, ad2, Hf, asb, adb, N_NODES);
    k_ew8<<<(N_EDGES_SL + 255) / 256, 256, 0, stream>>>(asb, adb, csrc, cdst, wbuf);
    k_agg8<<<2048, 256, 0, stream>>>(Hf, wbuf, offs, csrc, perm, b2, Ah, Al);

    // ---- conv3: K=512 (KB=16), Nn=64 (BN=64, NF=2) ----
    k_packW<64><<<(1 * 16 * 64 * 4 + 255) / 256, 256, 0, stream>>>(W3, Wh, Wl, F1, 64);
    k_gemm_mfma<16, 2><<<dim3(MB_TILES, 1), 256, 0, stream>>>(Ah, Al, Wh, Wl, Hf3, N_NODES, 64);
    k_alphas1<<<7500, 256, 0, stream>>>(Hf3, as3, ad3, asb1, adb1);
    k_ew1<<<(N_EDGES_SL + 255) / 256, 256, 0, stream>>>(asb1, adb1, csrc, cdst, w3);
    k_agg1<<<940, 256, 0, stream>>>(Hf3, w3, offs, csrc, perm, b3, h3);

    // ---- segmented mean-pool + fc ----
    k_poolfc<<<NGRAPH, 128, 0, stream>>>(h3, gstart, Wfc, bfc, out);
}

// Round 9
// 533.268 us; speedup vs baseline: 1.2343x; 1.2343x over previous
//
#include <hip/hip_runtime.h>
#include <hip/hip_fp16.h>
#include <math.h>

#define N_NODES 30000
#define N_EDGES 480000
#define N_EDGES_SL (N_EDGES + N_NODES)
#define DIM_IN 256
#define F1 512   // HEADS*HID
#define HEADS 8
#define NGRAPH 512
#define NEG 0.2f
#define MB_TILES 235  // ceil(30000/128)

typedef __attribute__((ext_vector_type(8))) short short8;
typedef __attribute__((ext_vector_type(4))) float f32x4;

__device__ __forceinline__ float lrelu(float x) { return x < 0.f ? NEG * x : x; }
__device__ __forceinline__ float elu_(float x) { return x > 0.f ? x : expm1f(x); }

// split fp32 -> bf16 hi + bf16 lo (round-to-nearest-even both)
__device__ __forceinline__ void cvt_split(float a, unsigned short& h, unsigned short& l) {
    unsigned u = __float_as_uint(a);
    unsigned hb = (u + 0x7fffu + ((u >> 16) & 1u)) >> 16;
    h = (unsigned short)hb;
    float res = a - __uint_as_float(hb << 16);
    unsigned v = __float_as_uint(res);
    l = (unsigned short)((v + 0x7fffu + ((v >> 16) & 1u)) >> 16);
}

// async global->LDS, 16B per lane
__device__ __forceinline__ void glds16(const unsigned short* g, unsigned short* l) {
    __builtin_amdgcn_global_load_lds(
        (const __attribute__((address_space(1))) unsigned int*)g,
        (__attribute__((address_space(3))) unsigned int*)l, 16, 0, 0);
}

// ---------------- CSR build ----------------
__global__ void k_count(const int* __restrict__ ei, int* __restrict__ deg) {
    int i = blockIdx.x * blockDim.x + threadIdx.x;
    if (i < N_EDGES) atomicAdd(&deg[ei[N_EDGES + i]], 1);
}

__global__ __launch_bounds__(256) void k_scan(const int* __restrict__ deg,
                                              int* __restrict__ offs,
                                              int* __restrict__ cursor) {
    const int T = 256;
    const int CH = (N_NODES + T - 1) / T;
    int t = threadIdx.x;
    int lo = t * CH;
    int hi = min(lo + CH, N_NODES);
    int s = 0;
    for (int i = lo; i < hi; ++i) s += deg[i] + 1;  // +1: self-loop
    __shared__ int part[T];
    part[t] = s;
    __syncthreads();
    for (int off = 1; off < T; off <<= 1) {
        int v = (t >= off) ? part[t - off] : 0;
        __syncthreads();
        part[t] += v;
        __syncthreads();
    }
    int run = part[t] - s;
    for (int i = lo; i < hi; ++i) {
        int d = deg[i];           // read BEFORE cursor write (cursor aliases deg)
        offs[i] = run;
        cursor[i] = run;
        run += d + 1;
    }
    if (t == T - 1) offs[N_NODES] = part[T - 1];
}

// scatter edges; also record dst per CSR slot (needed by edge-weight kernels)
__global__ void k_scatter(const int* __restrict__ ei, int* __restrict__ cursor,
                          int* __restrict__ csrc, int* __restrict__ cdst) {
    int i = blockIdx.x * blockDim.x + threadIdx.x;
    if (i >= N_EDGES_SL) return;
    int s, d;
    if (i < N_EDGES) { s = ei[i]; d = ei[N_EDGES + i]; }
    else { s = d = i - N_EDGES; }
    int p = atomicAdd(&cursor[d], 1);
    csrc[p] = s;
    cdst[p] = d;
}

// graph segment boundaries from SORTED batch
__global__ void k_bounds(const int* __restrict__ batch, int* __restrict__ gstart) {
    int i = blockIdx.x * blockDim.x + threadIdx.x;
    if (i >= N_NODES) return;
    int b = batch[i];
    int pb = (i == 0) ? -1 : batch[i - 1];
    for (int g = pb + 1; g <= b; ++g) gstart[g] = i;
    if (i == N_NODES - 1)
        for (int g = b + 1; g <= NGRAPH; ++g) gstart[g] = N_NODES;
}

// ---------------- pack A [M,K] fp32 -> [mb][kb][128][32] bf16 hi/lo ----------------
__global__ __launch_bounds__(256) void k_packA(const float* __restrict__ A,
                                               unsigned short* __restrict__ hi,
                                               unsigned short* __restrict__ lo,
                                               int M, int K) {
    int t = blockIdx.x * 256 + threadIdx.x;
    int KB = K >> 5;
    int MB = (M + 127) >> 7;
    int total = MB * KB * 512;
    if (t >= total) return;
    int k8 = t & 3;
    int ml = (t >> 2) & 127;
    int tmp = t >> 9;
    int kb = tmp % KB;
    int mb = tmp / KB;
    int m = mb * 128 + ml;
    int k0 = kb * 32 + k8 * 8;
    float v[8] = {0.f, 0.f, 0.f, 0.f, 0.f, 0.f, 0.f, 0.f};
    if (m < M) {
        float4 p0 = *(const float4*)(A + (size_t)m * K + k0);
        float4 p1 = *(const float4*)(A + (size_t)m * K + k0 + 4);
        v[0] = p0.x; v[1] = p0.y; v[2] = p0.z; v[3] = p0.w;
        v[4] = p1.x; v[5] = p1.y; v[6] = p1.z; v[7] = p1.w;
    }
    unsigned short h[8], l[8];
#pragma unroll
    for (int j = 0; j < 8; ++j) cvt_split(v[j], h[j], l[j]);
    size_t o = (size_t)t * 8;
    *(short8*)(hi + o) = *(short8*)h;
    *(short8*)(lo + o) = *(short8*)l;
}

// ---------------- pack W [K,Nn] fp32 -> [nb][kb][BN][32] bf16 hi/lo (n-major) -------
template <int BN>
__global__ __launch_bounds__(256) void k_packW(const float* __restrict__ W,
                                               unsigned short* __restrict__ hi,
                                               unsigned short* __restrict__ lo,
                                               int K, int Nn) {
    int t = blockIdx.x * 256 + threadIdx.x;
    int KB = K >> 5;
    int total = (Nn / BN) * KB * BN * 4;
    if (t >= total) return;
    constexpr int LB = (BN == 128) ? 7 : 6;
    int k8 = t & 3;
    int tmp = t >> 2;
    int nl = tmp & (BN - 1);
    int tmp2 = tmp >> LB;
    int kb = tmp2 % KB;
    int nb = tmp2 / KB;
    int n = nb * BN + nl;
    int k0 = kb * 32 + k8 * 8;
    unsigned short h[8], l[8];
#pragma unroll
    for (int j = 0; j < 8; ++j) cvt_split(W[(size_t)(k0 + j) * Nn + n], h[j], l[j]);
    size_t o = (size_t)t * 8;
    *(short8*)(hi + o) = *(short8*)h;
    *(short8*)(lo + o) = *(short8*)l;
}

// ---------------- split-bf16 MFMA GEMM, 8-head conv (Nn=512, BN=128, NF=4) ----------
// Epilogue: H fp16 head-split [head][node][64]; alphas [node][8].
template <int KB>
__global__ __launch_bounds__(256) void k_gemm8(const unsigned short* __restrict__ Ah,
                                               const unsigned short* __restrict__ Al,
                                               const unsigned short* __restrict__ Bh,
                                               const unsigned short* __restrict__ Bl,
                                               const float* __restrict__ a_src,
                                               const float* __restrict__ a_dst,
                                               __half* __restrict__ Hf,
                                               float* __restrict__ as_,
                                               float* __restrict__ ad_,
                                               int M) {
    __shared__ unsigned short sAh[4096], sAl[4096], sBh[4096], sBl[4096];
    const int tid = threadIdx.x, lane = tid & 63, wave = tid >> 6;
    const int mb = blockIdx.x, nb = blockIdx.y;
    const int wm = (wave >> 1) * 64;
    const int wn = (wave & 1) * 64;
    const int fr = lane & 15, quad = lane >> 4;

    const unsigned short* pAh = Ah + (size_t)mb * KB * 4096;
    const unsigned short* pAl = Al + (size_t)mb * KB * 4096;
    const unsigned short* pBh = Bh + (size_t)nb * KB * 4096;
    const unsigned short* pBl = Bl + (size_t)nb * KB * 4096;

    f32x4 acc[4][4];
#pragma unroll
    for (int i = 0; i < 4; ++i)
#pragma unroll
        for (int j = 0; j < 4; ++j) acc[i][j] = {0.f, 0.f, 0.f, 0.f};

    for (int kb = 0; kb < KB; ++kb) {
        const unsigned short* ah_g = pAh + kb * 4096;
        const unsigned short* al_g = pAl + kb * 4096;
        const unsigned short* bh_g = pBh + kb * 4096;
        const unsigned short* bl_g = pBl + kb * 4096;
#pragma unroll
        for (int s = 0; s < 2; ++s) {
            int sg = wave * 2 + s;
            glds16(ah_g + sg * 512 + lane * 8, &sAh[sg * 512]);
            glds16(al_g + sg * 512 + lane * 8, &sAl[sg * 512]);
            glds16(bh_g + sg * 512 + lane * 8, &sBh[sg * 512]);
            glds16(bl_g + sg * 512 + lane * 8, &sBl[sg * 512]);
        }
        __syncthreads();

        short8 af_h[4], af_l[4], bf_h[4], bf_l[4];
#pragma unroll
        for (int f = 0; f < 4; ++f) {
            int m = wm + f * 16 + fr;
            af_h[f] = *(const short8*)&sAh[m * 32 + quad * 8];
            af_l[f] = *(const short8*)&sAl[m * 32 + quad * 8];
            int n = wn + f * 16 + fr;
            bf_h[f] = *(const short8*)&sBh[n * 32 + quad * 8];
            bf_l[f] = *(const short8*)&sBl[n * 32 + quad * 8];
        }
#pragma unroll
        for (int i = 0; i < 4; ++i)
#pragma unroll
            for (int j = 0; j < 4; ++j) {
                acc[i][j] = __builtin_amdgcn_mfma_f32_16x16x32_bf16(af_h[i], bf_h[j], acc[i][j], 0, 0, 0);
                acc[i][j] = __builtin_amdgcn_mfma_f32_16x16x32_bf16(af_h[i], bf_l[j], acc[i][j], 0, 0, 0);
                acc[i][j] = __builtin_amdgcn_mfma_f32_16x16x32_bf16(af_l[i], bf_h[j], acc[i][j], 0, 0, 0);
            }
        __syncthreads();
    }
    // epilogue; C/D layout: col=lane&15, row=quad*4+reg
    const int head = (nb * 128 + wn) >> 6;  // wave's 64 cols = one head
    float avs[4], avd[4];
#pragma unroll
    for (int j = 0; j < 4; ++j) {
        avs[j] = a_src[head * 64 + j * 16 + fr];
        avd[j] = a_dst[head * 64 + j * 16 + fr];
    }
    __half* Hh = Hf + (size_t)head * N_NODES * 64;
#pragma unroll
    for (int i = 0; i < 4; ++i) {
#pragma unroll
        for (int r = 0; r < 4; ++r) {
            int row = mb * 128 + wm + i * 16 + quad * 4 + r;
            bool ok = row < M;
            float vs = 0.f, vd = 0.f;
#pragma unroll
            for (int j = 0; j < 4; ++j) {
                float c = acc[i][j][r];
                vs = fmaf(c, avs[j], vs);
                vd = fmaf(c, avd[j], vd);
                if (ok) Hh[(size_t)row * 64 + j * 16 + fr] = __float2half(c);
            }
#pragma unroll
            for (int off = 1; off < 16; off <<= 1) {
                vs += __shfl_xor(vs, off);
                vd += __shfl_xor(vd, off);
            }
            if (ok && fr == 0) {
                as_[(size_t)row * 8 + head] = vs;
                ad_[(size_t)row * 8 + head] = vd;
            }
        }
    }
}

// ---------------- split-bf16 MFMA GEMM, fp16 out (conv3: Nn=64) ----------
template <int KB, int NF>
__global__ __launch_bounds__(256) void k_gemm_mfma(const unsigned short* __restrict__ Ah,
                                                   const unsigned short* __restrict__ Al,
                                                   const unsigned short* __restrict__ Bh,
                                                   const unsigned short* __restrict__ Bl,
                                                   __half* __restrict__ C,
                                                   int M, int Nn) {
    constexpr int BN = NF * 32;
    constexpr int SBW = BN / 64;
    __shared__ unsigned short sAh[4096], sAl[4096], sBh[BN * 32], sBl[BN * 32];
    const int tid = threadIdx.x, lane = tid & 63, wave = tid >> 6;
    const int mb = blockIdx.x, nb = blockIdx.y;
    const int wm = (wave >> 1) * 64;
    const int wn = (wave & 1) * (BN / 2);
    const int fr = lane & 15, quad = lane >> 4;

    const unsigned short* pAh = Ah + (size_t)mb * KB * 4096;
    const unsigned short* pAl = Al + (size_t)mb * KB * 4096;
    const unsigned short* pBh = Bh + (size_t)nb * KB * (BN * 32);
    const unsigned short* pBl = Bl + (size_t)nb * KB * (BN * 32);

    f32x4 acc[4][NF];
#pragma unroll
    for (int i = 0; i < 4; ++i)
#pragma unroll
        for (int j = 0; j < NF; ++j) acc[i][j] = {0.f, 0.f, 0.f, 0.f};

    for (int kb = 0; kb < KB; ++kb) {
        const unsigned short* ah_g = pAh + kb * 4096;
        const unsigned short* al_g = pAl + kb * 4096;
        const unsigned short* bh_g = pBh + kb * (BN * 32);
        const unsigned short* bl_g = pBl + kb * (BN * 32);
#pragma unroll
        for (int s = 0; s < 2; ++s) {
            int sg = wave * 2 + s;
            glds16(ah_g + sg * 512 + lane * 8, &sAh[sg * 512]);
            glds16(al_g + sg * 512 + lane * 8, &sAl[sg * 512]);
        }
#pragma unroll
        for (int s = 0; s < SBW; ++s) {
            int sg = wave * SBW + s;
            glds16(bh_g + sg * 512 + lane * 8, &sBh[sg * 512]);
            glds16(bl_g + sg * 512 + lane * 8, &sBl[sg * 512]);
        }
        __syncthreads();

        short8 af_h[4], af_l[4], bf_h[NF], bf_l[NF];
#pragma unroll
        for (int f = 0; f < 4; ++f) {
            int m = wm + f * 16 + fr;
            af_h[f] = *(const short8*)&sAh[m * 32 + quad * 8];
            af_l[f] = *(const short8*)&sAl[m * 32 + quad * 8];
        }
#pragma unroll
        for (int f = 0; f < NF; ++f) {
            int n = wn + f * 16 + fr;
            bf_h[f] = *(const short8*)&sBh[n * 32 + quad * 8];
            bf_l[f] = *(const short8*)&sBl[n * 32 + quad * 8];
        }
#pragma unroll
        for (int i = 0; i < 4; ++i)
#pragma unroll
            for (int j = 0; j < NF; ++j) {
                acc[i][j] = __builtin_amdgcn_mfma_f32_16x16x32_bf16(af_h[i], bf_h[j], acc[i][j], 0, 0, 0);
                acc[i][j] = __builtin_amdgcn_mfma_f32_16x16x32_bf16(af_h[i], bf_l[j], acc[i][j], 0, 0, 0);
                acc[i][j] = __builtin_amdgcn_mfma_f32_16x16x32_bf16(af_l[i], bf_h[j], acc[i][j], 0, 0, 0);
            }
        __syncthreads();
    }
#pragma unroll
    for (int i = 0; i < 4; ++i) {
#pragma unroll
        for (int r = 0; r < 4; ++r) {
            int row = mb * 128 + wm + i * 16 + quad * 4 + r;
            if (row < M) {
#pragma unroll
                for (int j = 0; j < NF; ++j)
                    C[(size_t)row * Nn + nb * BN + wn + j * 16 + fr] =
                        __float2half(acc[i][j][r]);
            }
        }
    }
}

// ---------------- per-edge softmax weights, head-major [head][edge] ----------------
__global__ __launch_bounds__(256) void k_ew8(const float* __restrict__ as_,
                                             const float* __restrict__ ad_,
                                             const int* __restrict__ csrc,
                                             const int* __restrict__ cdst,
                                             float* __restrict__ wbuf) {
    int e = blockIdx.x * 256 + threadIdx.x;
    if (e >= N_EDGES_SL) return;
    int s = csrc[e], d = cdst[e];
    float4 a0 = *(const float4*)(as_ + (size_t)s * 8);
    float4 a1 = *(const float4*)(as_ + (size_t)s * 8 + 4);
    float4 d0 = *(const float4*)(ad_ + (size_t)d * 8);
    float4 d1 = *(const float4*)(ad_ + (size_t)d * 8 + 4);
    wbuf[0 * N_EDGES_SL + e] = __expf(lrelu(a0.x + d0.x));
    wbuf[1 * N_EDGES_SL + e] = __expf(lrelu(a0.y + d0.y));
    wbuf[2 * N_EDGES_SL + e] = __expf(lrelu(a0.z + d0.z));
    wbuf[3 * N_EDGES_SL + e] = __expf(lrelu(a0.w + d0.w));
    wbuf[4 * N_EDGES_SL + e] = __expf(lrelu(a1.x + d1.x));
    wbuf[5 * N_EDGES_SL + e] = __expf(lrelu(a1.y + d1.y));
    wbuf[6 * N_EDGES_SL + e] = __expf(lrelu(a1.z + d1.z));
    wbuf[7 * N_EDGES_SL + e] = __expf(lrelu(a1.w + d1.w));
}

// per-edge weights, 1 head (conv3)
__global__ __launch_bounds__(256) void k_ew1(const float* __restrict__ as_,
                                             const float* __restrict__ ad_,
                                             const int* __restrict__ csrc,
                                             const int* __restrict__ cdst,
                                             float* __restrict__ w3) {
    int e = blockIdx.x * 256 + threadIdx.x;
    if (e >= N_EDGES_SL) return;
    w3[e] = __expf(lrelu(as_[csrc[e]] + ad_[cdst[e]]));
}

// w * h (8 fp16 channels) -> fp32 acc; coaxes v_fma_mix_f32 (cvt folded into fma)
__device__ __forceinline__ void edge_fma(float w, uint4 u, float* a) {
    const _Float16* hp = (const _Float16*)&u;
#pragma unroll
    for (int k = 0; k < 8; ++k) a[k] = fmaf(w, (float)hp[k], a[k]);
}

// ---------------- softmax-aggregate (8 heads), head-split, XCD-affine --------------
// One wave = 8 dsts x 1 head (identity dst order — degree sort was a net loss, R8).
// Per edge: csrc idx + contiguous precomputed w + 16B H gather + 8 mix-fma + s+=w.
// head = blockIdx&7 pins head to XCD (2048 co-resident blocks).
__global__ __launch_bounds__(256) void k_agg8(const __half* __restrict__ Hf,
                                              const float* __restrict__ wbuf,
                                              const int* __restrict__ offs,
                                              const int* __restrict__ csrc,
                                              const float* __restrict__ bias,
                                              unsigned short* __restrict__ outh,
                                              unsigned short* __restrict__ outl) {
    const int head = blockIdx.x & 7;
    const int bg = blockIdx.x >> 3;  // 0..255
    const int wave = threadIdx.x >> 6, lane = threadIdx.x & 63;
    const int g = lane >> 3, cl = lane & 7;
    const __half* Hh = Hf + (size_t)head * N_NODES * 64;
    const float* wh = wbuf + (size_t)head * N_EDGES_SL;
    float bia[8];
#pragma unroll
    for (int j = 0; j < 8; ++j) bia[j] = bias[head * 64 + cl * 8 + j];

    // N_NODES % 8 == 0 -> every octet fully valid
    for (int d0 = (bg * 4 + wave) * 8; d0 < N_NODES; d0 += 8192) {
        int dst = d0 + g;
        int beg = offs[dst], end = offs[dst + 1];
        const int* cp = csrc + beg;
        const float* wp = wh + beg;
        int deg = end - beg;
        float s = 0.f;
        float a[8] = {0.f, 0.f, 0.f, 0.f, 0.f, 0.f, 0.f, 0.f};
        float b[8] = {0.f, 0.f, 0.f, 0.f, 0.f, 0.f, 0.f, 0.f};
        int loc = 0;
        for (; loc + 3 < deg; loc += 4) {
            int s0 = cp[loc], s1 = cp[loc + 1], s2 = cp[loc + 2], s3 = cp[loc + 3];
            float w0 = wp[loc], w1 = wp[loc + 1], w2 = wp[loc + 2], w3 = wp[loc + 3];
            uint4 u0 = *(const uint4*)(Hh + (size_t)s0 * 64 + cl * 8);
            uint4 u1 = *(const uint4*)(Hh + (size_t)s1 * 64 + cl * 8);
            uint4 u2 = *(const uint4*)(Hh + (size_t)s2 * 64 + cl * 8);
            uint4 u3 = *(const uint4*)(Hh + (size_t)s3 * 64 + cl * 8);
            s += (w0 + w1) + (w2 + w3);
            edge_fma(w0, u0, a);
            edge_fma(w1, u1, b);
            edge_fma(w2, u2, a);
            edge_fma(w3, u3, b);
        }
        for (; loc < deg; ++loc) {
            int s0 = cp[loc];
            float w = wp[loc];
            uint4 u = *(const uint4*)(Hh + (size_t)s0 * 64 + cl * 8);
            s += w;
            edge_fma(w, u, a);
        }
        float inv = 1.f / s;
        float o[8];
#pragma unroll
        for (int k = 0; k < 8; ++k) o[k] = elu_((a[k] + b[k]) * inv + bia[k]);
        unsigned short h[8], l[8];
#pragma unroll
        for (int k = 0; k < 8; ++k) cvt_split(o[k], h[k], l[k]);
        // packed A-tile write: global ch c0 = head*64 + cl*8
        int c0 = head * 64 + cl * 8;
        int kb = c0 >> 5, kl = c0 & 31;
        int mb = dst >> 7, ml = dst & 127;
        size_t oo = (((size_t)(mb * 16 + kb) * 128 + ml) * 32 + kl);
        *(short8*)(outh + oo) = *(short8*)h;
        *(short8*)(outl + oo) = *(short8*)l;
    }
}

// ---------------- conv3: 1 head x 64 ch ----------------
__global__ __launch_bounds__(256) void k_alphas1(const __half* __restrict__ H,
                                                 const float* __restrict__ a_src,
                                                 const float* __restrict__ a_dst,
                                                 float* __restrict__ as_,
                                                 float* __restrict__ ad_) {
    int wid = blockIdx.x * 4 + (threadIdx.x >> 6);
    int lane = threadIdx.x & 63;
    if (wid >= N_NODES) return;
    float h = __half2float(H[(size_t)wid * 64 + lane]);
    float ps = h * a_src[lane];
    float pd = h * a_dst[lane];
#pragma unroll
    for (int off = 1; off < 64; off <<= 1) {
        ps += __shfl_xor(ps, off);
        pd += __shfl_xor(pd, off);
    }
    if (lane == 0) { as_[wid] = ps; ad_[wid] = pd; }
}

// single-pass; precomputed w; writes h3 [node][64] fp32
__global__ __launch_bounds__(256) void k_agg1(const __half* __restrict__ Hf,
                                              const float* __restrict__ w3,
                                              const int* __restrict__ offs,
                                              const int* __restrict__ csrc,
                                              const float* __restrict__ bias,
                                              float* __restrict__ h3) {
    const int wave = threadIdx.x >> 6, lane = threadIdx.x & 63;
    const int g = lane >> 3, cl = lane & 7;
    int d0 = (blockIdx.x * 4 + wave) * 8;  // grid 940 -> 3760 octets >= 3750
    if (d0 >= N_NODES) return;
    int dst = d0 + g;
    float bia[8];
#pragma unroll
    for (int j = 0; j < 8; ++j) bia[j] = bias[cl * 8 + j];
    int beg = offs[dst], end = offs[dst + 1];
    const int* cp = csrc + beg;
    const float* wp = w3 + beg;
    int deg = end - beg;
    float s = 0.f;
    float a[8] = {0.f, 0.f, 0.f, 0.f, 0.f, 0.f, 0.f, 0.f};
    float b[8] = {0.f, 0.f, 0.f, 0.f, 0.f, 0.f, 0.f, 0.f};
    int loc = 0;
    for (; loc + 3 < deg; loc += 4) {
        int s0 = cp[loc], s1 = cp[loc + 1], s2 = cp[loc + 2], s3 = cp[loc + 3];
        float w0 = wp[loc], w1 = wp[loc + 1], w2 = wp[loc + 2], w3v = wp[loc + 3];
        uint4 u0 = *(const uint4*)(Hf + (size_t)s0 * 64 + cl * 8);
        uint4 u1 = *(const uint4*)(Hf + (size_t)s1 * 64 + cl * 8);
        uint4 u2 = *(const uint4*)(Hf + (size_t)s2 * 64 + cl * 8);
        uint4 u3 = *(const uint4*)(Hf + (size_t)s3 * 64 + cl * 8);
        s += (w0 + w1) + (w2 + w3v);
        edge_fma(w0, u0, a);
        edge_fma(w1, u1, b);
        edge_fma(w2, u2, a);
        edge_fma(w3v, u3, b);
    }
    for (; loc < deg; ++loc) {
        int s0 = cp[loc];
        float w = wp[loc];
        uint4 u = *(const uint4*)(Hf + (size_t)s0 * 64 + cl * 8);
        s += w;
        edge_fma(w, u, a);
    }
    float inv = 1.f / s;
    float o[8];
#pragma unroll
    for (int k = 0; k < 8; ++k) o[k] = elu_((a[k] + b[k]) * inv + bia[k]);
    float* op = h3 + (size_t)dst * 64 + cl * 8;
    *(float4*)op = make_float4(o[0], o[1], o[2], o[3]);
    *(float4*)(op + 4) = make_float4(o[4], o[5], o[6], o[7]);
}

// ---------------- segmented mean-pool (sorted batch) + fc, no atomics ----------
__global__ __launch_bounds__(128) void k_poolfc(const float* __restrict__ h3,
                                                const int* __restrict__ gstart,
                                                const float* __restrict__ W,
                                                const float* __restrict__ b,
                                                float* __restrict__ out) {
    int g = blockIdx.x;
    int t = threadIdx.x;  // 128
    int s0 = gstart[g], s1 = gstart[g + 1];
    int c = t & 63, half = t >> 6;
    float acc = 0.f;
    for (int r = s0 + half; r < s1; r += 2) acc += h3[(size_t)r * 64 + c];
    __shared__ float p2[128];
    __shared__ float p[64];
    p2[t] = acc;
    __syncthreads();
    if (t < 64) {
        float cntf = (float)(s1 - s0);
        p[t] = (p2[t] + p2[t + 64]) / fmaxf(cntf, 1.f);
    }
    __syncthreads();
    float o = b[t];
#pragma unroll
    for (int k = 0; k < 64; ++k) o = fmaf(p[k], W[k * 128 + t], o);
    out[g * 128 + t] = o;
}

extern "C" void kernel_launch(void* const* d_in, const int* in_sizes, int n_in,
                              void* d_out, int out_size, void* d_ws, size_t ws_size,
                              hipStream_t stream) {
    const float* x     = (const float*)d_in[0];
    const int*   ei    = (const int*)d_in[1];
    const int*   batch = (const int*)d_in[2];
    const float* W1    = (const float*)d_in[3];
    const float* as1   = (const float*)d_in[4];
    const float* ad1   = (const float*)d_in[5];
    const float* b1    = (const float*)d_in[6];
    const float* W2    = (const float*)d_in[7];
    const float* as2   = (const float*)d_in[8];
    const float* ad2   = (const float*)d_in[9];
    const float* b2    = (const float*)d_in[10];
    const float* W3    = (const float*)d_in[11];
    const float* as3   = (const float*)d_in[12];
    const float* ad3   = (const float*)d_in[13];
    const float* b3    = (const float*)d_in[14];
    const float* Wfc   = (const float*)d_in[15];
    const float* bfc   = (const float*)d_in[16];
    float* out = (float*)d_out;

    char* ws = (char*)d_ws;
    size_t off = 0;
    auto alloc = [&](size_t bytes) -> void* {
        void* p = ws + off;
        off += (bytes + 255) & ~(size_t)255;
        return p;
    };
    __half* Hf = (__half*)alloc((size_t)HEADS * N_NODES * 64 * 2);  // [head][node][64]
    __half* Hf3 = (__half*)alloc((size_t)N_NODES * 64 * 2);
    float* h3 = (float*)alloc((size_t)N_NODES * 64 * 4);
    unsigned short* Ah = (unsigned short*)alloc((size_t)MB_TILES * 16 * 4096 * 2);
    unsigned short* Al = (unsigned short*)alloc((size_t)MB_TILES * 16 * 4096 * 2);
    unsigned short* Wh = (unsigned short*)alloc((size_t)262144 * 2);
    unsigned short* Wl = (unsigned short*)alloc((size_t)262144 * 2);
    float* asb   = (float*)alloc((size_t)N_NODES * 8 * 4);   // [node][8]
    float* adb   = (float*)alloc((size_t)N_NODES * 8 * 4);
    float* asb1  = (float*)alloc((size_t)N_NODES * 4);       // conv3 [node]
    float* adb1  = (float*)alloc((size_t)N_NODES * 4);
    float* wbuf  = (float*)alloc((size_t)HEADS * N_EDGES_SL * 4);  // [head][edge]
    float* w3    = (float*)alloc((size_t)N_EDGES_SL * 4);
    int*   offs  = (int*)alloc((N_NODES + 1) * 4);
    int*   deg   = (int*)alloc(N_NODES * 4);   // reused as scatter cursor
    int*   csrc  = (int*)alloc((size_t)N_EDGES_SL * 4);
    int*   cdst  = (int*)alloc((size_t)N_EDGES_SL * 4);
    int*   gstart= (int*)alloc((NGRAPH + 1) * 4);

    hipMemsetAsync(deg, 0, N_NODES * 4, stream);

    k_count<<<(N_EDGES + 255) / 256, 256, 0, stream>>>(ei, deg);
    k_scan<<<1, 256, 0, stream>>>(deg, offs, deg);
    k_scatter<<<(N_EDGES_SL + 255) / 256, 256, 0, stream>>>(ei, deg, csrc, cdst);
    k_bounds<<<(N_NODES + 255) / 256, 256, 0, stream>>>(batch, gstart);

    // ---- conv1: K=256 (KB=8) ----
    k_packA<<<(MB_TILES * 8 * 512 + 255) / 256, 256, 0, stream>>>(x, Ah, Al, N_NODES, DIM_IN);
    k_packW<128><<<(4 * 8 * 128 * 4 + 255) / 256, 256, 0, stream>>>(W1, Wh, Wl, DIM_IN, F1);
    k_gemm8<8><<<dim3(MB_TILES, 4), 256, 0, stream>>>(Ah, Al, Wh, Wl, as1, ad1, Hf, asb, adb, N_NODES);
    k_ew8<<<(N_EDGES_SL + 255) / 256, 256, 0, stream>>>(asb, adb, csrc, cdst, wbuf);
    k_agg8<<<2048, 256, 0, stream>>>(Hf, wbuf, offs, csrc, b1, Ah, Al);

    // ---- conv2: K=512 (KB=16) ----
    k_packW<128><<<(4 * 16 * 128 * 4 + 255) / 256, 256, 0, stream>>>(W2, Wh, Wl, F1, F1);
    k_gemm8<16><<<dim3(MB_TILES, 4), 256, 0, stream>>>(Ah, Al, Wh, Wl, as2, ad2, Hf, asb, adb, N_NODES);
    k_ew8<<<(N_EDGES_SL + 255) / 256, 256, 0, stream>>>(asb, adb, csrc, cdst, wbuf);
    k_agg8<<<2048, 256, 0, stream>>>(Hf, wbuf, offs, csrc, b2, Ah, Al);

    // ---- conv3: K=512 (KB=16), Nn=64 (BN=64, NF=2) ----
    k_packW<64><<<(1 * 16 * 64 * 4 + 255) / 256, 256, 0, stream>>>(W3, Wh, Wl, F1, 64);
    k_gemm_mfma<16, 2><<<dim3(MB_TILES, 1), 256, 0, stream>>>(Ah, Al, Wh, Wl, Hf3, N_NODES, 64);
    k_alphas1<<<7500, 256, 0, stream>>>(Hf3, as3, ad3, asb1, adb1);
    k_ew1<<<(N_EDGES_SL + 255) / 256, 256, 0, stream>>>(asb1, adb1, csrc, cdst, w3);
    k_agg1<<<940, 256, 0, stream>>>(Hf3, w3, offs, csrc, b3, h3);

    // ---- segmented mean-pool + fc ----
    k_poolfc<<<NGRAPH, 128, 0, stream>>>(h3, gstart, Wfc, bfc, out);
}

// Round 10
// 458.924 us; speedup vs baseline: 1.4343x; 1.1620x over previous
//
#include <hip/hip_runtime.h>
#include <hip/hip_fp16.h>
#include <math.h>

#define N_NODES 30000
#define N_EDGES 480000
#define N_EDGES_SL (N_EDGES + N_NODES)
#define DIM_IN 256
#define F1 512   // HEADS*HID
#define HEADS 8
#define NGRAPH 512
#define NEG 0.2f
#define MB_TILES 235  // ceil(30000/128)
#define NB_SCAN 118   // ceil(30000/256)

typedef __attribute__((ext_vector_type(8))) short short8;
typedef __attribute__((ext_vector_type(4))) float f32x4;

__device__ __forceinline__ float lrelu(float x) { return x < 0.f ? NEG * x : x; }
__device__ __forceinline__ float elu_(float x) { return x > 0.f ? x : expm1f(x); }

// split fp32 -> bf16 hi + bf16 lo (round-to-nearest-even both)
__device__ __forceinline__ void cvt_split(float a, unsigned short& h, unsigned short& l) {
    unsigned u = __float_as_uint(a);
    unsigned hb = (u + 0x7fffu + ((u >> 16) & 1u)) >> 16;
    h = (unsigned short)hb;
    float res = a - __uint_as_float(hb << 16);
    unsigned v = __float_as_uint(res);
    l = (unsigned short)((v + 0x7fffu + ((v >> 16) & 1u)) >> 16);
}

// async global->LDS, 16B per lane
__device__ __forceinline__ void glds16(const unsigned short* g, unsigned short* l) {
    __builtin_amdgcn_global_load_lds(
        (const __attribute__((address_space(1))) unsigned int*)g,
        (__attribute__((address_space(3))) unsigned int*)l, 16, 0, 0);
}

// ---------------- CSR build ----------------
__global__ void k_count(const int* __restrict__ ei, int* __restrict__ deg) {
    int i = blockIdx.x * blockDim.x + threadIdx.x;
    if (i < N_EDGES) atomicAdd(&deg[ei[N_EDGES + i]], 1);
}

// 3-phase parallel scan (old single-block k_scan was 72 us, serialized on 1 CU)
__global__ __launch_bounds__(256) void k_bsum(const int* __restrict__ deg,
                                              int* __restrict__ bsum) {
    int i = blockIdx.x * 256 + threadIdx.x;
    int v = (i < N_NODES) ? deg[i] + 1 : 0;  // +1: self-loop
#pragma unroll
    for (int off = 1; off < 64; off <<= 1) v += __shfl_xor(v, off);
    __shared__ int ws[4];
    if ((threadIdx.x & 63) == 0) ws[threadIdx.x >> 6] = v;
    __syncthreads();
    if (threadIdx.x == 0) bsum[blockIdx.x] = ws[0] + ws[1] + ws[2] + ws[3];
}

__global__ __launch_bounds__(128) void k_bscan(const int* __restrict__ bsum,
                                               int* __restrict__ bbase,
                                               int* __restrict__ offsN) {
    __shared__ int p[128];
    int t = threadIdx.x;
    int v = (t < NB_SCAN) ? bsum[t] : 0;
    p[t] = v;
    __syncthreads();
    for (int off = 1; off < 128; off <<= 1) {
        int x = (t >= off) ? p[t - off] : 0;
        __syncthreads();
        p[t] += x;
        __syncthreads();
    }
    if (t < NB_SCAN) bbase[t] = p[t] - v;  // exclusive
    if (t == 127) *offsN = p[127];         // grand total -> offs[N_NODES]
}

__global__ __launch_bounds__(256) void k_offs(const int* __restrict__ deg,
                                              const int* __restrict__ bbase,
                                              int* __restrict__ offs,
                                              int* __restrict__ cursor) {
    int b = blockIdx.x, t = threadIdx.x;
    int i = b * 256 + t;
    int v = (i < N_NODES) ? deg[i] + 1 : 0;  // read BEFORE cursor write (aliases deg)
    __shared__ int p[256];
    p[t] = v;
    __syncthreads();
    for (int off = 1; off < 256; off <<= 1) {
        int x = (t >= off) ? p[t - off] : 0;
        __syncthreads();
        p[t] += x;
        __syncthreads();
    }
    if (i < N_NODES) {
        int excl = bbase[b] + p[t] - v;
        offs[i] = excl;
        cursor[i] = excl;
    }
}

__global__ void k_scatter(const int* __restrict__ ei, int* __restrict__ cursor,
                          int* __restrict__ csrc) {
    int i = blockIdx.x * blockDim.x + threadIdx.x;
    if (i >= N_EDGES_SL) return;
    int s, d;
    if (i < N_EDGES) { s = ei[i]; d = ei[N_EDGES + i]; }
    else { s = d = i - N_EDGES; }
    int p = atomicAdd(&cursor[d], 1);
    csrc[p] = s;
}

// graph segment boundaries from SORTED batch
__global__ void k_bounds(const int* __restrict__ batch, int* __restrict__ gstart) {
    int i = blockIdx.x * blockDim.x + threadIdx.x;
    if (i >= N_NODES) return;
    int b = batch[i];
    int pb = (i == 0) ? -1 : batch[i - 1];
    for (int g = pb + 1; g <= b; ++g) gstart[g] = i;
    if (i == N_NODES - 1)
        for (int g = b + 1; g <= NGRAPH; ++g) gstart[g] = N_NODES;
}

// ---------------- pack A [M,K] fp32 -> [mb][kb][128][32] bf16 hi/lo ----------------
__global__ __launch_bounds__(256) void k_packA(const float* __restrict__ A,
                                               unsigned short* __restrict__ hi,
                                               unsigned short* __restrict__ lo,
                                               int M, int K) {
    int t = blockIdx.x * 256 + threadIdx.x;
    int KB = K >> 5;
    int MB = (M + 127) >> 7;
    int total = MB * KB * 512;
    if (t >= total) return;
    int k8 = t & 3;
    int ml = (t >> 2) & 127;
    int tmp = t >> 9;
    int kb = tmp % KB;
    int mb = tmp / KB;
    int m = mb * 128 + ml;
    int k0 = kb * 32 + k8 * 8;
    float v[8] = {0.f, 0.f, 0.f, 0.f, 0.f, 0.f, 0.f, 0.f};
    if (m < M) {
        float4 p0 = *(const float4*)(A + (size_t)m * K + k0);
        float4 p1 = *(const float4*)(A + (size_t)m * K + k0 + 4);
        v[0] = p0.x; v[1] = p0.y; v[2] = p0.z; v[3] = p0.w;
        v[4] = p1.x; v[5] = p1.y; v[6] = p1.z; v[7] = p1.w;
    }
    unsigned short h[8], l[8];
#pragma unroll
    for (int j = 0; j < 8; ++j) cvt_split(v[j], h[j], l[j]);
    size_t o = (size_t)t * 8;
    *(short8*)(hi + o) = *(short8*)h;
    *(short8*)(lo + o) = *(short8*)l;
}

// ---------------- pack W [K,Nn] fp32 -> [nb][kb][BN][32] bf16 hi/lo (n-major) -------
template <int BN>
__global__ __launch_bounds__(256) void k_packW(const float* __restrict__ W,
                                               unsigned short* __restrict__ hi,
                                               unsigned short* __restrict__ lo,
                                               int K, int Nn) {
    int t = blockIdx.x * 256 + threadIdx.x;
    int KB = K >> 5;
    int total = (Nn / BN) * KB * BN * 4;
    if (t >= total) return;
    constexpr int LB = (BN == 128) ? 7 : 6;
    int k8 = t & 3;
    int tmp = t >> 2;
    int nl = tmp & (BN - 1);
    int tmp2 = tmp >> LB;
    int kb = tmp2 % KB;
    int nb = tmp2 / KB;
    int n = nb * BN + nl;
    int k0 = kb * 32 + k8 * 8;
    unsigned short h[8], l[8];
#pragma unroll
    for (int j = 0; j < 8; ++j) cvt_split(W[(size_t)(k0 + j) * Nn + n], h[j], l[j]);
    size_t o = (size_t)t * 8;
    *(short8*)(hi + o) = *(short8*)h;
    *(short8*)(lo + o) = *(short8*)l;
}

// ---------------- split-bf16 MFMA GEMM, 8-head conv (Nn=512, BN=128, NF=4) ----------
// Fused epilogue: H fp16 head-split [head][node][64]; alphas head-split [head][node].
template <int KB>
__global__ __launch_bounds__(256) void k_gemm8(const unsigned short* __restrict__ Ah,
                                               const unsigned short* __restrict__ Al,
                                               const unsigned short* __restrict__ Bh,
                                               const unsigned short* __restrict__ Bl,
                                               const float* __restrict__ a_src,
                                               const float* __restrict__ a_dst,
                                               __half* __restrict__ Hf,
                                               float* __restrict__ as_,
                                               float* __restrict__ ad_,
                                               int M) {
    __shared__ unsigned short sAh[4096], sAl[4096], sBh[4096], sBl[4096];
    const int tid = threadIdx.x, lane = tid & 63, wave = tid >> 6;
    const int mb = blockIdx.x, nb = blockIdx.y;
    const int wm = (wave >> 1) * 64;
    const int wn = (wave & 1) * 64;
    const int fr = lane & 15, quad = lane >> 4;

    const unsigned short* pAh = Ah + (size_t)mb * KB * 4096;
    const unsigned short* pAl = Al + (size_t)mb * KB * 4096;
    const unsigned short* pBh = Bh + (size_t)nb * KB * 4096;
    const unsigned short* pBl = Bl + (size_t)nb * KB * 4096;

    f32x4 acc[4][4];
#pragma unroll
    for (int i = 0; i < 4; ++i)
#pragma unroll
        for (int j = 0; j < 4; ++j) acc[i][j] = {0.f, 0.f, 0.f, 0.f};

    for (int kb = 0; kb < KB; ++kb) {
        const unsigned short* ah_g = pAh + kb * 4096;
        const unsigned short* al_g = pAl + kb * 4096;
        const unsigned short* bh_g = pBh + kb * 4096;
        const unsigned short* bl_g = pBl + kb * 4096;
#pragma unroll
        for (int s = 0; s < 2; ++s) {
            int sg = wave * 2 + s;
            glds16(ah_g + sg * 512 + lane * 8, &sAh[sg * 512]);
            glds16(al_g + sg * 512 + lane * 8, &sAl[sg * 512]);
            glds16(bh_g + sg * 512 + lane * 8, &sBh[sg * 512]);
            glds16(bl_g + sg * 512 + lane * 8, &sBl[sg * 512]);
        }
        __syncthreads();

        short8 af_h[4], af_l[4], bf_h[4], bf_l[4];
#pragma unroll
        for (int f = 0; f < 4; ++f) {
            int m = wm + f * 16 + fr;
            af_h[f] = *(const short8*)&sAh[m * 32 + quad * 8];
            af_l[f] = *(const short8*)&sAl[m * 32 + quad * 8];
            int n = wn + f * 16 + fr;
            bf_h[f] = *(const short8*)&sBh[n * 32 + quad * 8];
            bf_l[f] = *(const short8*)&sBl[n * 32 + quad * 8];
        }
#pragma unroll
        for (int i = 0; i < 4; ++i)
#pragma unroll
            for (int j = 0; j < 4; ++j) {
                acc[i][j] = __builtin_amdgcn_mfma_f32_16x16x32_bf16(af_h[i], bf_h[j], acc[i][j], 0, 0, 0);
                acc[i][j] = __builtin_amdgcn_mfma_f32_16x16x32_bf16(af_h[i], bf_l[j], acc[i][j], 0, 0, 0);
                acc[i][j] = __builtin_amdgcn_mfma_f32_16x16x32_bf16(af_l[i], bf_h[j], acc[i][j], 0, 0, 0);
            }
        __syncthreads();
    }
    // epilogue; C/D layout: col=lane&15, row=quad*4+reg
    const int head = (nb * 128 + wn) >> 6;  // wave's 64 cols = one head
    float avs[4], avd[4];
#pragma unroll
    for (int j = 0; j < 4; ++j) {
        avs[j] = a_src[head * 64 + j * 16 + fr];
        avd[j] = a_dst[head * 64 + j * 16 + fr];
    }
    __half* Hh = Hf + (size_t)head * N_NODES * 64;
#pragma unroll
    for (int i = 0; i < 4; ++i) {
#pragma unroll
        for (int r = 0; r < 4; ++r) {
            int row = mb * 128 + wm + i * 16 + quad * 4 + r;
            bool ok = row < M;
            float vs = 0.f, vd = 0.f;
#pragma unroll
            for (int j = 0; j < 4; ++j) {
                float c = acc[i][j][r];
                vs = fmaf(c, avs[j], vs);
                vd = fmaf(c, avd[j], vd);
                if (ok) Hh[(size_t)row * 64 + j * 16 + fr] = __float2half(c);
            }
#pragma unroll
            for (int off = 1; off < 16; off <<= 1) {
                vs += __shfl_xor(vs, off);
                vd += __shfl_xor(vd, off);
            }
            if (ok && fr == 0) {
                as_[head * N_NODES + row] = vs;
                ad_[head * N_NODES + row] = vd;
            }
        }
    }
}

// ---------------- split-bf16 MFMA GEMM, fp16 out (conv3: Nn=64) ----------
template <int KB, int NF>
__global__ __launch_bounds__(256) void k_gemm_mfma(const unsigned short* __restrict__ Ah,
                                                   const unsigned short* __restrict__ Al,
                                                   const unsigned short* __restrict__ Bh,
                                                   const unsigned short* __restrict__ Bl,
                                                   __half* __restrict__ C,
                                                   int M, int Nn) {
    constexpr int BN = NF * 32;
    constexpr int SBW = BN / 64;
    __shared__ unsigned short sAh[4096], sAl[4096], sBh[BN * 32], sBl[BN * 32];
    const int tid = threadIdx.x, lane = tid & 63, wave = tid >> 6;
    const int mb = blockIdx.x, nb = blockIdx.y;
    const int wm = (wave >> 1) * 64;
    const int wn = (wave & 1) * (BN / 2);
    const int fr = lane & 15, quad = lane >> 4;

    const unsigned short* pAh = Ah + (size_t)mb * KB * 4096;
    const unsigned short* pAl = Al + (size_t)mb * KB * 4096;
    const unsigned short* pBh = Bh + (size_t)nb * KB * (BN * 32);
    const unsigned short* pBl = Bl + (size_t)nb * KB * (BN * 32);

    f32x4 acc[4][NF];
#pragma unroll
    for (int i = 0; i < 4; ++i)
#pragma unroll
        for (int j = 0; j < NF; ++j) acc[i][j] = {0.f, 0.f, 0.f, 0.f};

    for (int kb = 0; kb < KB; ++kb) {
        const unsigned short* ah_g = pAh + kb * 4096;
        const unsigned short* al_g = pAl + kb * 4096;
        const unsigned short* bh_g = pBh + kb * (BN * 32);
        const unsigned short* bl_g = pBl + kb * (BN * 32);
#pragma unroll
        for (int s = 0; s < 2; ++s) {
            int sg = wave * 2 + s;
            glds16(ah_g + sg * 512 + lane * 8, &sAh[sg * 512]);
            glds16(al_g + sg * 512 + lane * 8, &sAl[sg * 512]);
        }
#pragma unroll
        for (int s = 0; s < SBW; ++s) {
            int sg = wave * SBW + s;
            glds16(bh_g + sg * 512 + lane * 8, &sBh[sg * 512]);
            glds16(bl_g + sg * 512 + lane * 8, &sBl[sg * 512]);
        }
        __syncthreads();

        short8 af_h[4], af_l[4], bf_h[NF], bf_l[NF];
#pragma unroll
        for (int f = 0; f < 4; ++f) {
            int m = wm + f * 16 + fr;
            af_h[f] = *(const short8*)&sAh[m * 32 + quad * 8];
            af_l[f] = *(const short8*)&sAl[m * 32 + quad * 8];
        }
#pragma unroll
        for (int f = 0; f < NF; ++f) {
            int n = wn + f * 16 + fr;
            bf_h[f] = *(const short8*)&sBh[n * 32 + quad * 8];
            bf_l[f] = *(const short8*)&sBl[n * 32 + quad * 8];
        }
#pragma unroll
        for (int i = 0; i < 4; ++i)
#pragma unroll
            for (int j = 0; j < NF; ++j) {
                acc[i][j] = __builtin_amdgcn_mfma_f32_16x16x32_bf16(af_h[i], bf_h[j], acc[i][j], 0, 0, 0);
                acc[i][j] = __builtin_amdgcn_mfma_f32_16x16x32_bf16(af_h[i], bf_l[j], acc[i][j], 0, 0, 0);
                acc[i][j] = __builtin_amdgcn_mfma_f32_16x16x32_bf16(af_l[i], bf_h[j], acc[i][j], 0, 0, 0);
            }
        __syncthreads();
    }
#pragma unroll
    for (int i = 0; i < 4; ++i) {
#pragma unroll
        for (int r = 0; r < 4; ++r) {
            int row = mb * 128 + wm + i * 16 + quad * 4 + r;
            if (row < M) {
#pragma unroll
                for (int j = 0; j < NF; ++j)
                    C[(size_t)row * Nn + nb * BN + wn + j * 16 + fr] =
                        __float2half(acc[i][j][r]);
            }
        }
    }
}

// process one gathered edge: w*H[src] into 8-channel accumulator
__device__ __forceinline__ void edge_fma(float w, uint4 u, float* a) {
    const _Float16* hp = (const _Float16*)&u;
#pragma unroll
    for (int k = 0; k < 8; ++k) a[k] = fmaf(w, (float)hp[k], a[k]);
}

// ---------------- softmax-aggregate (8 heads), head-split, XCD-affine --------------
// One wave = 8 dsts x 1 head; lane owns (dst = lane>>3, 8 ch = lane&7). Single pass,
// inline exp (R7-measured structure; ew-precompute variants regressed in R8/R9).
// 4-deep gather pipeline. head = blockIdx&7 pins head to XCD (2048 blocks).
__global__ __launch_bounds__(256) void k_agg8(const __half* __restrict__ Hf,
                                              const float* __restrict__ as_,
                                              const float* __restrict__ ad_,
                                              const int* __restrict__ offs,
                                              const int* __restrict__ csrc,
                                              const float* __restrict__ bias,
                                              unsigned short* __restrict__ outh,
                                              unsigned short* __restrict__ outl) {
    const int head = blockIdx.x & 7;
    const int bg = blockIdx.x >> 3;  // 0..255
    const int wave = threadIdx.x >> 6, lane = threadIdx.x & 63;
    const int g = lane >> 3, cl = lane & 7;
    const __half* Hh = Hf + (size_t)head * N_NODES * 64;
    const float* ash = as_ + head * N_NODES;
    const float* adh = ad_ + head * N_NODES;
    float bia[8];
#pragma unroll
    for (int j = 0; j < 8; ++j) bia[j] = bias[head * 64 + cl * 8 + j];

    // N_NODES % 8 == 0 -> every octet fully valid
    for (int d0 = (bg * 4 + wave) * 8; d0 < N_NODES; d0 += 8192) {
        int dst = d0 + g;
        int beg = offs[dst], end = offs[dst + 1];
        float adv = adh[dst];
        const int* cp = csrc + beg;
        int deg = end - beg;
        float s = 0.f;
        float a[8] = {0.f, 0.f, 0.f, 0.f, 0.f, 0.f, 0.f, 0.f};
        float b[8] = {0.f, 0.f, 0.f, 0.f, 0.f, 0.f, 0.f, 0.f};
        int loc = 0;
        for (; loc + 3 < deg; loc += 4) {
            int s0 = cp[loc], s1 = cp[loc + 1], s2 = cp[loc + 2], s3 = cp[loc + 3];
            float e0 = ash[s0], e1 = ash[s1], e2 = ash[s2], e3 = ash[s3];
            uint4 u0 = *(const uint4*)(Hh + (size_t)s0 * 64 + cl * 8);
            uint4 u1 = *(const uint4*)(Hh + (size_t)s1 * 64 + cl * 8);
            uint4 u2 = *(const uint4*)(Hh + (size_t)s2 * 64 + cl * 8);
            uint4 u3 = *(const uint4*)(Hh + (size_t)s3 * 64 + cl * 8);
            float w0 = __expf(lrelu(e0 + adv));
            float w1 = __expf(lrelu(e1 + adv));
            float w2 = __expf(lrelu(e2 + adv));
            float w3 = __expf(lrelu(e3 + adv));
            s += (w0 + w1) + (w2 + w3);
            edge_fma(w0, u0, a);
            edge_fma(w1, u1, b);
            edge_fma(w2, u2, a);
            edge_fma(w3, u3, b);
        }
        for (; loc < deg; ++loc) {
            int s0 = cp[loc];
            float w = __expf(lrelu(ash[s0] + adv));
            uint4 u = *(const uint4*)(Hh + (size_t)s0 * 64 + cl * 8);
            s += w;
            edge_fma(w, u, a);
        }
        float inv = 1.f / s;
        float o[8];
#pragma unroll
        for (int k = 0; k < 8; ++k) o[k] = elu_((a[k] + b[k]) * inv + bia[k]);
        unsigned short h[8], l[8];
#pragma unroll
        for (int k = 0; k < 8; ++k) cvt_split(o[k], h[k], l[k]);
        // packed A-tile write: global ch c0 = head*64 + cl*8
        int c0 = head * 64 + cl * 8;
        int kb = c0 >> 5, kl = c0 & 31;
        int mb = dst >> 7, ml = dst & 127;
        size_t oo = (((size_t)(mb * 16 + kb) * 128 + ml) * 32 + kl);
        *(short8*)(outh + oo) = *(short8*)h;
        *(short8*)(outl + oo) = *(short8*)l;
    }
}

// ---------------- conv3: 1 head x 64 ch ----------------
__global__ __launch_bounds__(256) void k_alphas1(const __half* __restrict__ H,
                                                 const float* __restrict__ a_src,
                                                 const float* __restrict__ a_dst,
                                                 float* __restrict__ as_,
                                                 float* __restrict__ ad_) {
    int wid = blockIdx.x * 4 + (threadIdx.x >> 6);
    int lane = threadIdx.x & 63;
    if (wid >= N_NODES) return;
    float h = __half2float(H[(size_t)wid * 64 + lane]);
    float ps = h * a_src[lane];
    float pd = h * a_dst[lane];
#pragma unroll
    for (int off = 1; off < 64; off <<= 1) {
        ps += __shfl_xor(ps, off);
        pd += __shfl_xor(pd, off);
    }
    if (lane == 0) { as_[wid] = ps; ad_[wid] = pd; }
}

// single-pass, 4-deep pipeline; writes h3 [node][64] fp32
__global__ __launch_bounds__(256) void k_agg1(const __half* __restrict__ Hf,
                                              const float* __restrict__ as_,
                                              const float* __restrict__ ad_,
                                              const int* __restrict__ offs,
                                              const int* __restrict__ csrc,
                                              const float* __restrict__ bias,
                                              float* __restrict__ h3) {
    const int wave = threadIdx.x >> 6, lane = threadIdx.x & 63;
    const int g = lane >> 3, cl = lane & 7;
    int d0 = (blockIdx.x * 4 + wave) * 8;  // grid 940 -> 3760 octets >= 3750
    if (d0 >= N_NODES) return;
    int dst = d0 + g;
    float bia[8];
#pragma unroll
    for (int j = 0; j < 8; ++j) bia[j] = bias[cl * 8 + j];
    int beg = offs[dst], end = offs[dst + 1];
    float adv = ad_[dst];
    const int* cp = csrc + beg;
    int deg = end - beg;
    float s = 0.f;
    float a[8] = {0.f, 0.f, 0.f, 0.f, 0.f, 0.f, 0.f, 0.f};
    float b[8] = {0.f, 0.f, 0.f, 0.f, 0.f, 0.f, 0.f, 0.f};
    int loc = 0;
    for (; loc + 3 < deg; loc += 4) {
        int s0 = cp[loc], s1 = cp[loc + 1], s2 = cp[loc + 2], s3 = cp[loc + 3];
        float e0 = as_[s0], e1 = as_[s1], e2 = as_[s2], e3 = as_[s3];
        uint4 u0 = *(const uint4*)(Hf + (size_t)s0 * 64 + cl * 8);
        uint4 u1 = *(const uint4*)(Hf + (size_t)s1 * 64 + cl * 8);
        uint4 u2 = *(const uint4*)(Hf + (size_t)s2 * 64 + cl * 8);
        uint4 u3 = *(const uint4*)(Hf + (size_t)s3 * 64 + cl * 8);
        float w0 = __expf(lrelu(e0 + adv));
        float w1 = __expf(lrelu(e1 + adv));
        float w2 = __expf(lrelu(e2 + adv));
        float w3 = __expf(lrelu(e3 + adv));
        s += (w0 + w1) + (w2 + w3);
        edge_fma(w0, u0, a);
        edge_fma(w1, u1, b);
        edge_fma(w2, u2, a);
        edge_fma(w3, u3, b);
    }
    for (; loc < deg; ++loc) {
        int s0 = cp[loc];
        float w = __expf(lrelu(as_[s0] + adv));
        uint4 u = *(const uint4*)(Hf + (size_t)s0 * 64 + cl * 8);
        s += w;
        edge_fma(w, u, a);
    }
    float inv = 1.f / s;
    float o[8];
#pragma unroll
    for (int k = 0; k < 8; ++k) o[k] = elu_((a[k] + b[k]) * inv + bia[k]);
    float* op = h3 + (size_t)dst * 64 + cl * 8;
    *(float4*)op = make_float4(o[0], o[1], o[2], o[3]);
    *(float4*)(op + 4) = make_float4(o[4], o[5], o[6], o[7]);
}

// ---------------- segmented mean-pool (sorted batch) + fc, no atomics ----------
__global__ __launch_bounds__(128) void k_poolfc(const float* __restrict__ h3,
                                                const int* __restrict__ gstart,
                                                const float* __restrict__ W,
                                                const float* __restrict__ b,
                                                float* __restrict__ out) {
    int g = blockIdx.x;
    int t = threadIdx.x;  // 128
    int s0 = gstart[g], s1 = gstart[g + 1];
    int c = t & 63, half = t >> 6;
    float acc = 0.f;
    for (int r = s0 + half; r < s1; r += 2) acc += h3[(size_t)r * 64 + c];
    __shared__ float p2[128];
    __shared__ float p[64];
    p2[t] = acc;
    __syncthreads();
    if (t < 64) {
        float cntf = (float)(s1 - s0);
        p[t] = (p2[t] + p2[t + 64]) / fmaxf(cntf, 1.f);
    }
    __syncthreads();
    float o = b[t];
#pragma unroll
    for (int k = 0; k < 64; ++k) o = fmaf(p[k], W[k * 128 + t], o);
    out[g * 128 + t] = o;
}

extern "C" void kernel_launch(void* const* d_in, const int* in_sizes, int n_in,
                              void* d_out, int out_size, void* d_ws, size_t ws_size,
                              hipStream_t stream) {
    const float* x     = (const float*)d_in[0];
    const int*   ei    = (const int*)d_in[1];
    const int*   batch = (const int*)d_in[2];
    const float* W1    = (const float*)d_in[3];
    const float* as1   = (const float*)d_in[4];
    const float* ad1   = (const float*)d_in[5];
    const float* b1    = (const float*)d_in[6];
    const float* W2    = (const float*)d_in[7];
    const float* as2   = (const float*)d_in[8];
    const float* ad2   = (const float*)d_in[9];
    const float* b2    = (const float*)d_in[10];
    const float* W3    = (const float*)d_in[11];
    const float* as3   = (const float*)d_in[12];
    const float* ad3   = (const float*)d_in[13];
    const float* b3    = (const float*)d_in[14];
    const float* Wfc   = (const float*)d_in[15];
    const float* bfc   = (const float*)d_in[16];
    float* out = (float*)d_out;

    char* ws = (char*)d_ws;
    size_t off = 0;
    auto alloc = [&](size_t bytes) -> void* {
        void* p = ws + off;
        off += (bytes + 255) & ~(size_t)255;
        return p;
    };
    __half* Hf = (__half*)alloc((size_t)HEADS * N_NODES * 64 * 2);  // [head][node][64]
    __half* Hf3 = (__half*)alloc((size_t)N_NODES * 64 * 2);
    float* h3 = (float*)alloc((size_t)N_NODES * 64 * 4);
    unsigned short* Ah = (unsigned short*)alloc((size_t)MB_TILES * 16 * 4096 * 2);
    unsigned short* Al = (unsigned short*)alloc((size_t)MB_TILES * 16 * 4096 * 2);
    unsigned short* Wh = (unsigned short*)alloc((size_t)262144 * 2);
    unsigned short* Wl = (unsigned short*)alloc((size_t)262144 * 2);
    float* asb   = (float*)alloc((size_t)HEADS * N_NODES * 4);  // [head][node]
    float* adb   = (float*)alloc((size_t)HEADS * N_NODES * 4);
    int*   offs  = (int*)alloc((N_NODES + 1) * 4);
    int*   deg   = (int*)alloc(N_NODES * 4);   // reused as scatter cursor
    int*   csrc  = (int*)alloc((size_t)N_EDGES_SL * 4);
    int*   bsum  = (int*)alloc(NB_SCAN * 4);
    int*   bbase = (int*)alloc(NB_SCAN * 4);
    int*   gstart= (int*)alloc((NGRAPH + 1) * 4);

    hipMemsetAsync(deg, 0, N_NODES * 4, stream);

    // CSR build: count -> 3-phase parallel scan -> scatter
    k_count<<<(N_EDGES + 255) / 256, 256, 0, stream>>>(ei, deg);
    k_bsum<<<NB_SCAN, 256, 0, stream>>>(deg, bsum);
    k_bscan<<<1, 128, 0, stream>>>(bsum, bbase, offs + N_NODES);
    k_offs<<<NB_SCAN, 256, 0, stream>>>(deg, bbase, offs, deg);
    k_scatter<<<(N_EDGES_SL + 255) / 256, 256, 0, stream>>>(ei, deg, csrc);
    k_bounds<<<(N_NODES + 255) / 256, 256, 0, stream>>>(batch, gstart);

    // ---- conv1: K=256 (KB=8) ----
    k_packA<<<(MB_TILES * 8 * 512 + 255) / 256, 256, 0, stream>>>(x, Ah, Al, N_NODES, DIM_IN);
    k_packW<128><<<(4 * 8 * 128 * 4 + 255) / 256, 256, 0, stream>>>(W1, Wh, Wl, DIM_IN, F1);
    k_gemm8<8><<<dim3(MB_TILES, 4), 256, 0, stream>>>(Ah, Al, Wh, Wl, as1, ad1, Hf, asb, adb, N_NODES);
    k_agg8<<<2048, 256, 0, stream>>>(Hf, asb, adb, offs, csrc, b1, Ah, Al);

    // ---- conv2: K=512 (KB=16) ----
    k_packW<128><<<(4 * 16 * 128 * 4 + 255) / 256, 256, 0, stream>>>(W2, Wh, Wl, F1, F1);
    k_gemm8<16><<<dim3(MB_TILES, 4), 256, 0, stream>>>(Ah, Al, Wh, Wl, as2, ad2, Hf, asb, adb, N_NODES);
    k_agg8<<<2048, 256, 0, stream>>>(Hf, asb, adb, offs, csrc, b2, Ah, Al);

    // ---- conv3: K=512 (KB=16), Nn=64 (BN=64, NF=2) ----
    k_packW<64><<<(1 * 16 * 64 * 4 + 255) / 256, 256, 0, stream>>>(W3, Wh, Wl, F1, 64);
    k_gemm_mfma<16, 2><<<dim3(MB_TILES, 1), 256, 0, stream>>>(Ah, Al, Wh, Wl, Hf3, N_NODES, 64);
    k_alphas1<<<7500, 256, 0, stream>>>(Hf3, as3, ad3, asb, adb);
    k_agg1<<<940, 256, 0, stream>>>(Hf3, asb, adb, offs, csrc, b3, h3);

    // ---- segmented mean-pool + fc ----
    k_poolfc<<<NGRAPH, 128, 0, stream>>>(h3, gstart, Wfc, bfc, out);
}